// Round 14
// baseline (420.324 us; speedup 1.0000x reference)
//
#include <hip/hip_runtime.h>

#define NPTS 150000
#define NHEAD 5
#define KTOT 1152
#define NTILES 1172   // ceil(150000/128)
#define NBLK 586      // ceil(150000/256)
#define HSTRIDE 592   // padded NBLK for hist_t rows
#define EPSV 1e-5f
#define FXSCALE 1048576.0   // 2^20 fixed-point for deterministic atomics

typedef __bf16 bf16x8 __attribute__((ext_vector_type(8)));
typedef float f32x4 __attribute__((ext_vector_type(4)));
typedef unsigned short u16x8 __attribute__((ext_vector_type(8)));

// ws layout (bytes):
//   xbf      @ 0          : 150016*128*2      = 38,404,096
//   w1t      @ 38404096   : 5*128*1152*2      =  1,474,560   (pre-swizzled B^T)
//   accw2    @ 39878656   : 150016*640*2      = 192,020,480  (PERMUTED rows, [gr][640])
//     pre-GEMM aliases: hist_t @ accw2+0 (512*592*4) ; tot @ +2,097,152 (2 KB)
//   sacc     @ 231899136  : 1280*8            =     10,240   (int64 fixed-point stats)
//   perm     @ 231909376  : 150000*4          =    600,000
//   iperm    @ 232509376  : 150000*4          =    600,000
#define WS_NEEDED 233109376UL

__device__ __forceinline__ unsigned short f2bf(float f) {
    unsigned int u = __float_as_uint(f);
    u += 0x7FFFu + ((u >> 16) & 1u);          // round-to-nearest-even
    return (unsigned short)(u >> 16);
}

__device__ __forceinline__ void gload16(const void* g, void* l) {
    __builtin_amdgcn_global_load_lds((const __attribute__((address_space(1))) void*)g,
                                     (__attribute__((address_space(3))) void*)l, 16, 0, 0);
}

// ---- fused pre-pass: convert x -> xbf | W1 -> w1t (swizzled) | pattern hist --
__global__ void k_pre(const float* __restrict__ x, unsigned short* __restrict__ xbf,
                      const float* __restrict__ W1, unsigned short* __restrict__ w1t,
                      const int* __restrict__ nbr, int* __restrict__ hist_t) {
    __shared__ int lh[512];
    const int bid = blockIdx.x;
    const int t = threadIdx.x;
    if (bid < 9376) {                     // ---- convert ----
        const size_t i8 = (size_t)bid * 256 + t;
        const size_t base = i8 * 8;
        if (base >= (size_t)(NPTS + 1) * 128) return;
        if (base < (size_t)NPTS * 128) {
            const f32x4 v0 = __builtin_nontemporal_load((const f32x4*)(x + base));
            const f32x4 v1 = __builtin_nontemporal_load((const f32x4*)(x + base + 4));
            u16x8 o;
            o[0] = f2bf(v0[0]); o[1] = f2bf(v0[1]); o[2] = f2bf(v0[2]); o[3] = f2bf(v0[3]);
            o[4] = f2bf(v1[0]); o[5] = f2bf(v1[1]); o[6] = f2bf(v1[2]); o[7] = f2bf(v1[3]);
            *(u16x8*)(xbf + base) = o;
        } else {
            u16x8 z = {0,0,0,0,0,0,0,0};
            *(u16x8*)(xbf + base) = z;
        }
    } else if (bid < 9376 + 2880) {       // ---- w1t (B^T, 4-block swizzle/32-short seg) ----
        const int idx = (bid - 9376) * 256 + t;
        const int d = idx & 127;
        const int c = (idx >> 7) & 127;
        const int hk = idx >> 14;
        const int k = hk % 9, h = hk / 9;
        const int col = h * 128 + d;
        const int p = k * 128 + c;
        const int s32 = p >> 5;
        const int j0 = (p >> 3) & 3;
        const int jj = j0 ^ ((col >> 1) & 3);
        w1t[(size_t)col * KTOT + s32 * 32 + jj * 8 + (p & 7)] = f2bf(W1[idx]);
    } else {                              // ---- hist ----
        const int b = bid - 12256;
        lh[t] = 0; lh[t + 256] = 0;
        __syncthreads();
        const int n = b * 256 + t;
        if (n < NPTS) {
            int pat = 0;
#pragma unroll
            for (int k = 0; k < 9; k++) pat |= (nbr[n * 9 + k] != NPTS) << k;
            atomicAdd(&lh[pat], 1);
        }
        __syncthreads();
        hist_t[t * HSTRIDE + b] = lh[t];
        hist_t[(t + 256) * HSTRIDE + b] = lh[t + 256];
    }
}

// ---- sort B1: per-pattern exclusive scan over blocks (in-place) + zero sacc --
__global__ void k_scan1(int* __restrict__ hist_t, int* __restrict__ tot,
                        unsigned long long* __restrict__ sacc) {
    const int p = blockIdx.x;
    const int lane = threadIdx.x;
    if (lane == 0) {                      // zero stats accumulators (1280 = 512+512+256)
        sacc[p] = 0ULL; sacc[512 + p] = 0ULL;
        if (p < 256) sacc[1024 + p] = 0ULL;
    }
    int run = 0;
    for (int c = 0; c < 10; c++) {
        const int i = c * 64 + lane;
        const int orig = (i < NBLK) ? hist_t[p * HSTRIDE + i] : 0;
        int v = orig;
        for (int d = 1; d < 64; d <<= 1) {
            const int w = __shfl_up(v, d);
            if (lane >= d) v += w;
        }
        if (i < NBLK) hist_t[p * HSTRIDE + i] = run + v - orig;
        run += __shfl(v, 63);
    }
    if (lane == 0) tot[p] = run;
}

// ---- sort C: base-scan (fused) + stable rank-scatter into perm/iperm ---------
__global__ __launch_bounds__(512) void k_scatter(
    const int* __restrict__ nbr, const int* __restrict__ hist_t,
    const int* __restrict__ tot, int* __restrict__ perm, int* __restrict__ iperm) {
    __shared__ int pat_s[256];
    __shared__ int bs[512];
    const int t = threadIdx.x, b = blockIdx.x;
    const int v0 = tot[t];
    bs[t] = v0;
    __syncthreads();
    for (int d = 1; d < 512; d <<= 1) {
        const int w = (t >= d) ? bs[t - d] : 0;
        __syncthreads();
        bs[t] += w;
        __syncthreads();
    }
    const int base_t = bs[t] - v0;        // exclusive prefix
    __syncthreads();
    bs[t] = base_t;
    const int n = b * 256 + (t & 255);
    int pat = -1;
    if (t < 256) {
        if (n < NPTS) {
            pat = 0;
#pragma unroll
            for (int k = 0; k < 9; k++) pat |= (nbr[n * 9 + k] != NPTS) << k;
        }
        pat_s[t] = pat;
    }
    __syncthreads();
    if (t < 256 && n < NPTS) {
        int rank = 0;
        for (int j = 0; j < 256; j++) rank += (j < t) & (pat_s[j] == pat);
        const int dest = bs[pat] + hist_t[pat * HSTRIDE + b] + rank;
        perm[dest] = n;
        iperm[n] = dest;
    }
}

// ------- pass 3: sparse gather-GEMM (R12 core), dense [gr][640] C-store -------
__global__ __launch_bounds__(512, 4) void k_gemm(
    const unsigned short* __restrict__ xbf,
    const unsigned short* __restrict__ w1t,
    const int* __restrict__ nbr,
    const int* __restrict__ perm,
    unsigned short* __restrict__ accw2,
    unsigned long long* __restrict__ sacc)
{
    // A dbuf shorts [0,8192) ; B dbuf shorts [8192,28672)
    // epilogue alias: C 128x168 shorts [0,21504)
    __shared__ unsigned short ABC[28672];            // 57,344 B
    __shared__ int nbr_s[9 * 128];
    __shared__ int perm_s[128];
    __shared__ int mask_s;

    const int tid = threadIdx.x;
    const int wid = tid >> 6;
    const int lane = tid & 63;
    const int bm = blockIdx.x;
    const int b2 = blockIdx.y;              // which 320-col half
    const int tile = (bm * 331) % NTILES;   // spread heavy tiles (331 coprime to 1172)
    const int tile0 = tile * 128;

    if (tid == 0) mask_s = 0;
    if (tid < 128) {
        const int gr = tile0 + tid;
        perm_s[tid] = (gr < NPTS) ? perm[gr] : NPTS;
    }
    __syncthreads();
    if (tid < 128) {
        const int prow = perm_s[tid];
        int pat = 0;
#pragma unroll
        for (int k = 0; k < 9; k++) {
            const int v = (prow < NPTS) ? nbr[prow * 9 + k] : NPTS;
            nbr_s[k * 128 + tid] = v;
            pat |= (v != NPTS) << k;
        }
        if (pat) atomicOr(&mask_s, pat);
    }
    __syncthreads();
    const int mask = mask_s | 16;
    const int steps = 4 * __builtin_popcount(mask);

    const int RM = (wid >> 2) * 64;          // 2 row-groups of 64
    const int CNl = (wid & 3) * 80;          // 4 col-groups of 80
    const int lr16 = lane >> 2;              // staging: 16 rows/segment
    const int lb = lane & 3;                 // staging: 4 x 16B blocks/row
    const int jswS = (lb ^ ((lr16 >> 1) & 3)) * 8;   // A source swizzle

    f32x4 acc[4][5];
#pragma unroll
    for (int m = 0; m < 4; m++)
#pragma unroll
        for (int n = 0; n < 5; n++) acc[m][n] = f32x4{0.f, 0.f, 0.f, 0.f};

    // stage one BK=32 K-slab: A 8 segs + B 20 segs of 1 KB
    auto stage = [&](int buf, int kn, int q) {
#pragma unroll
        for (int j = 0; j < 4; ++j) {
            const int g = wid + 8 * j;               // wave-uniform
            if (g < 8) {                             // A rows g*16..+15
                const int r = g * 16 + lr16;
                const int idx = nbr_s[kn * 128 + r];
                gload16(xbf + (size_t)idx * 128 + q * 32 + jswS,
                        (void*)(ABC + buf * 4096 + g * 512));
            } else if (g < 28) {                     // B cols (g-8)*16..+15
                const int gb = g - 8;
                const int lc = gb * 16 + lr16;
                gload16(w1t + (size_t)(b2 * 320 + lc) * KTOT + (kn * 4 + q) * 32 + lb * 8,
                        (void*)(ABC + 8192 + buf * 10240 + gb * 512));
            }
        }
    };

    const int rlo = lane & 15;
    const int jsw = (((lane >> 4) ^ ((rlo >> 1) & 3))) * 8;  // read swizzle

    auto compute = [&](int buf) {
        const unsigned short* Ab = ABC + buf * 4096;
        const unsigned short* Bb = ABC + 8192 + buf * 10240;
        bf16x8 a[4];
#pragma unroll
        for (int m = 0; m < 4; m++)
            a[m] = *reinterpret_cast<const bf16x8*>(&Ab[(RM + m * 16 + rlo) * 32 + jsw]);
#pragma unroll
        for (int n = 0; n < 5; n++) {
            const bf16x8 b = *reinterpret_cast<const bf16x8*>(&Bb[(CNl + n * 16 + rlo) * 32 + jsw]);
#pragma unroll
            for (int m = 0; m < 4; m++)
                acc[m][n] = __builtin_amdgcn_mfma_f32_16x16x32_bf16(a[m], b, acc[m][n], 0, 0, 0);
        }
    };

    // walk (kn, q=0..3) over set bits of mask; prefetch-before-compute
    int ckn = __builtin_ctz(mask), cq = 0, rem = mask & (mask - 1), buf = 0;
    stage(0, ckn, 0);
    __syncthreads();
    for (int i = 0; i < steps; i++) {
        int nkn, nq, nrem;
        if (cq < 3) { nkn = ckn; nq = cq + 1; nrem = rem; }
        else { nkn = rem ? __builtin_ctz(rem) : 0; nq = 0; nrem = rem & (rem - 1); }
        if (i + 1 < steps) stage(buf ^ 1, nkn, nq);
        compute(buf);
        __syncthreads();
        ckn = nkn; cq = nq; rem = nrem; buf ^= 1;
    }

    // ---- per-column sums/sumsq -> fixed-point int64 atomics (deterministic) ----
    float sn[5], qn[5];
#pragma unroll
    for (int n = 0; n < 5; n++) {
        float s = 0.f, q = 0.f;
#pragma unroll
        for (int m = 0; m < 4; m++)
#pragma unroll
            for (int r = 0; r < 4; r++) { const float v = acc[m][n][r]; s += v; q += v * v; }
        s += __shfl_xor(s, 16); s += __shfl_xor(s, 32);
        q += __shfl_xor(q, 16); q += __shfl_xor(q, 32);
        sn[n] = s; qn[n] = q;
    }
    if (lane < 16) {
#pragma unroll
        for (int n = 0; n < 5; n++) {
            const int gcol = b2 * 320 + CNl + n * 16 + lane;
            atomicAdd(&sacc[gcol],
                      (unsigned long long)__double2ll_rn((double)sn[n] * FXSCALE));
            atomicAdd(&sacc[640 + gcol],
                      (unsigned long long)__double2ll_rn((double)qn[n] * FXSCALE));
        }
    }

    // ---- C store via LDS transpose into dense [gr][640] rows (no straddle) ----
    unsigned short* C = (unsigned short*)ABC;            // 128 x 168 per pass
#pragma unroll
    for (int p = 0; p < 2; ++p) {
        __syncthreads();
        if (((wid >> 1) & 1) == p) {                     // waves owning cols p*160..+159
            const int colbase = CNl - p * 160;           // 0 or 80
#pragma unroll
            for (int m = 0; m < 4; m++) {
                const int row = RM + m * 16 + (lane >> 4) * 4;
#pragma unroll
                for (int n = 0; n < 5; n++) {
                    const int col = colbase + n * 16 + rlo;
#pragma unroll
                    for (int r = 0; r < 4; r++)
                        C[(row + r) * 168 + col] = f2bf(acc[m][n][r]);
                }
            }
        }
        __syncthreads();
#pragma unroll
        for (int j = 0; j < 5; j++) {
            const int chunk = tid + 512 * j;             // 2560 = 128 rows x 20 chunks
            const int row = chunk / 20, cc = chunk % 20;
            const int gr = tile0 + row;                  // sequential permuted row (<150016)
            const int col = b2 * 320 + p * 160 + cc * 8;
            __builtin_nontemporal_store(*(const u16x8*)&C[row * 168 + cc * 8],
                (u16x8*)(accw2 + (size_t)gr * 640 + col));
        }
    }
}

// ------- pass 4: stats + normalize + relu + W2 + bias + mask (all heads) ------
__global__ __launch_bounds__(512) void k_out(
    const unsigned short* __restrict__ accw2,
    const int* __restrict__ iperm,
    const unsigned long long* __restrict__ sacc,
    const float* __restrict__ gamma, const float* __restrict__ beta,
    const float* __restrict__ W2, const float* __restrict__ b2,
    float* __restrict__ out)
{
    __shared__ float sc[640], sh[640], w2s[1920], b2s[15];
    __shared__ int ip_s[128];
    __shared__ float red[128][4][6];
    const int t = threadIdx.x;
    for (int c = t; c < 640; c += 512) {
        const double s = (double)(long long)sacc[c] * (1.0 / FXSCALE);
        const double q = (double)(long long)sacc[640 + c] * (1.0 / FXSCALE);
        const double mean = s * (1.0 / NPTS);
        const double var = q * (1.0 / NPTS) - mean * mean;
        const float rstd = (float)(1.0 / sqrt(var + (double)EPSV));
        const float g = gamma[c];
        sc[c] = rstd * g;
        sh[c] = beta[c] - (float)mean * rstd * g;
        w2s[c * 3 + 0] = W2[c * 3 + 0];
        w2s[c * 3 + 1] = W2[c * 3 + 1];
        w2s[c * 3 + 2] = W2[c * 3 + 2];
    }
    if (t < 15) b2s[t] = b2[t];
    if (t < 128) {
        const int n = blockIdx.x * 128 + t;
        ip_s[t] = (n < NPTS) ? iperm[n] : -1;
    }
    __syncthreads();

    const int row = t >> 2;                   // 128 rows/block, 4 threads/row
    const int seg = t & 3;                    // 160 cols each; head splits at ccb
    const int r = ip_s[row];
    const int ccb = 16 - seg * 4;             // 16B-chunk index where head increments
    float o0[3] = {0.f, 0.f, 0.f}, o1[3] = {0.f, 0.f, 0.f};
    if (r >= 0) {
        const unsigned short* rp = accw2 + (size_t)r * 640 + seg * 160;
        for (int cc = 0; cc < ccb; cc++) {    // section 0 -> head seg
            const u16x8 v = __builtin_nontemporal_load((const u16x8*)(rp + cc * 8));
#pragma unroll
            for (int j = 0; j < 8; j++) {
                const int c = seg * 160 + cc * 8 + j;
                const float a = __uint_as_float(((unsigned int)v[j]) << 16);
                const float hc = fmaxf(fmaf(a, sc[c], sh[c]), 0.f);
                o0[0] = fmaf(hc, w2s[c * 3 + 0], o0[0]);
                o0[1] = fmaf(hc, w2s[c * 3 + 1], o0[1]);
                o0[2] = fmaf(hc, w2s[c * 3 + 2], o0[2]);
            }
        }
        for (int cc = ccb; cc < 20; cc++) {   // section 1 -> head seg+1
            const u16x8 v = __builtin_nontemporal_load((const u16x8*)(rp + cc * 8));
#pragma unroll
            for (int j = 0; j < 8; j++) {
                const int c = seg * 160 + cc * 8 + j;
                const float a = __uint_as_float(((unsigned int)v[j]) << 16);
                const float hc = fmaxf(fmaf(a, sc[c], sh[c]), 0.f);
                o1[0] = fmaf(hc, w2s[c * 3 + 0], o1[0]);
                o1[1] = fmaf(hc, w2s[c * 3 + 1], o1[1]);
                o1[2] = fmaf(hc, w2s[c * 3 + 2], o1[2]);
            }
        }
    }
    red[row][seg][0] = o0[0]; red[row][seg][1] = o0[1]; red[row][seg][2] = o0[2];
    red[row][seg][3] = o1[0]; red[row][seg][4] = o1[1]; red[row][seg][5] = o1[2];
    __syncthreads();

    // combine: head h <- seg h-1 section1 + seg h section0 ; write coalesced per head
    for (int idx = t; idx < 640; idx += 512) {
        const int h = idx >> 7, rw = idx & 127;
        const int n = blockIdx.x * 128 + rw;
        if (n < NPTS) {
            float a0 = b2s[h * 3 + 0], a1 = b2s[h * 3 + 1], a2 = b2s[h * 3 + 2];
            if (h >= 1) { a0 += red[rw][h - 1][3]; a1 += red[rw][h - 1][4]; a2 += red[rw][h - 1][5]; }
            if (h <= 3) { a0 += red[rw][h][0]; a1 += red[rw][h][1]; a2 += red[rw][h][2]; }
            const int noc = (h == 2) ? 1 : ((h == 1 || h == 4) ? 2 : 3);
            const size_t ob = ((size_t)h * NPTS + n) * 3;
            out[ob + 0] = (noc > 0) ? a0 : 0.f;
            out[ob + 1] = (noc > 1) ? a1 : 0.f;
            out[ob + 2] = (noc > 2) ? a2 : 0.f;
        }
    }
}

__global__ void k_sentinel(float* __restrict__ out, int n) {
    const int i = blockIdx.x * 256 + threadIdx.x;
    if (i < n) out[i] = 12345.0f;
}

extern "C" void kernel_launch(void* const* d_in, const int* in_sizes, int n_in,
                              void* d_out, int out_size, void* d_ws, size_t ws_size,
                              hipStream_t stream) {
    const float* x     = (const float*)d_in[0];
    const int*   nbr   = (const int*)d_in[1];
    const float* W1    = (const float*)d_in[2];
    const float* gamma = (const float*)d_in[3];
    const float* beta  = (const float*)d_in[4];
    const float* W2    = (const float*)d_in[5];
    const float* b2    = (const float*)d_in[6];
    float* out = (float*)d_out;

    if (ws_size < WS_NEEDED) {
        k_sentinel<<<(out_size + 255) / 256, 256, 0, stream>>>(out, out_size);
        return;
    }

    char* ws = (char*)d_ws;
    unsigned short* xbf      = (unsigned short*)(ws);
    unsigned short* w1t      = (unsigned short*)(ws + 38404096);
    unsigned short* accw2    = (unsigned short*)(ws + 39878656);
    int*            hist_t   = (int*)(ws + 39878656);            // aliases accw2 (pre-GEMM)
    int*            tot      = (int*)(ws + 39878656 + 2097152);  // aliases accw2 (pre-GEMM)
    unsigned long long* sacc = (unsigned long long*)(ws + 231899136);
    int*            perm     = (int*)(ws + 231909376);
    int*            iperm    = (int*)(ws + 232509376);

    k_pre<<<12842, 256, 0, stream>>>(x, xbf, W1, w1t, nbr, hist_t);
    k_scan1<<<512, 64, 0, stream>>>(hist_t, tot, sacc);
    k_scatter<<<NBLK, 512, 0, stream>>>(nbr, hist_t, tot, perm, iperm);
    k_gemm<<<dim3(NTILES, 2), 512, 0, stream>>>(xbf, w1t, nbr, perm, accw2, sacc);
    k_out<<<NTILES, 512, 0, stream>>>(accw2, iperm, sacc, gamma, beta, W2, b2, out);
}

// Round 15
// 356.395 us; speedup vs baseline: 1.1794x; 1.1794x over previous
//
#include <hip/hip_runtime.h>

#define NPTS 150000
#define NHEAD 5
#define KTOT 1152
#define NTILES 1172   // ceil(150000/128)
#define NBLK 586      // ceil(150000/256)
#define HSTRIDE 592   // padded NBLK for hist_t rows
#define EPSV 1e-5f
#define FXSCALE 1048576.0   // 2^20 fixed-point for deterministic atomics

typedef __bf16 bf16x8 __attribute__((ext_vector_type(8)));
typedef float f32x4 __attribute__((ext_vector_type(4)));
typedef unsigned short u16x8 __attribute__((ext_vector_type(8)));

// ws layout (bytes):
//   xbf      @ 0          : 150016*128*2      = 38,404,096
//   w1t      @ 38404096   : 5*128*1152*2      =  1,474,560   (pre-swizzled B^T)
//   accw2    @ 39878656   : 150016*640*2      = 192,020,480  (ORIGINAL row order, [n][640])
//     pre-GEMM aliases: hist_t @ accw2+0 (512*592*4) ; tot @ +2,097,152 (2 KB)
//   sacc     @ 231899136  : 1280*8            =     10,240   (int64 fixed-point stats)
//   perm     @ 231909376  : 150000*4          =    600,000
#define WS_NEEDED 232509376UL

__device__ __forceinline__ unsigned short f2bf(float f) {
    unsigned int u = __float_as_uint(f);
    u += 0x7FFFu + ((u >> 16) & 1u);          // round-to-nearest-even
    return (unsigned short)(u >> 16);
}

__device__ __forceinline__ void gload16(const void* g, void* l) {
    __builtin_amdgcn_global_load_lds((const __attribute__((address_space(1))) void*)g,
                                     (__attribute__((address_space(3))) void*)l, 16, 0, 0);
}

// ---- fused pre-pass: convert x -> xbf | W1 -> w1t (swizzled) | pattern hist --
__global__ void k_pre(const float* __restrict__ x, unsigned short* __restrict__ xbf,
                      const float* __restrict__ W1, unsigned short* __restrict__ w1t,
                      const int* __restrict__ nbr, int* __restrict__ hist_t) {
    __shared__ int lh[512];
    const int bid = blockIdx.x;
    const int t = threadIdx.x;
    if (bid < 9376) {                     // ---- convert ----
        const size_t i8 = (size_t)bid * 256 + t;
        const size_t base = i8 * 8;
        if (base >= (size_t)(NPTS + 1) * 128) return;
        if (base < (size_t)NPTS * 128) {
            const f32x4 v0 = __builtin_nontemporal_load((const f32x4*)(x + base));
            const f32x4 v1 = __builtin_nontemporal_load((const f32x4*)(x + base + 4));
            u16x8 o;
            o[0] = f2bf(v0[0]); o[1] = f2bf(v0[1]); o[2] = f2bf(v0[2]); o[3] = f2bf(v0[3]);
            o[4] = f2bf(v1[0]); o[5] = f2bf(v1[1]); o[6] = f2bf(v1[2]); o[7] = f2bf(v1[3]);
            *(u16x8*)(xbf + base) = o;
        } else {
            u16x8 z = {0,0,0,0,0,0,0,0};
            *(u16x8*)(xbf + base) = z;
        }
    } else if (bid < 9376 + 2880) {       // ---- w1t (B^T, 4-block swizzle/32-short seg) ----
        const int idx = (bid - 9376) * 256 + t;
        const int d = idx & 127;
        const int c = (idx >> 7) & 127;
        const int hk = idx >> 14;
        const int k = hk % 9, h = hk / 9;
        const int col = h * 128 + d;
        const int p = k * 128 + c;
        const int s32 = p >> 5;
        const int j0 = (p >> 3) & 3;
        const int jj = j0 ^ ((col >> 1) & 3);
        w1t[(size_t)col * KTOT + s32 * 32 + jj * 8 + (p & 7)] = f2bf(W1[idx]);
    } else {                              // ---- hist ----
        const int b = bid - 12256;
        lh[t] = 0; lh[t + 256] = 0;
        __syncthreads();
        const int n = b * 256 + t;
        if (n < NPTS) {
            int pat = 0;
#pragma unroll
            for (int k = 0; k < 9; k++) pat |= (nbr[n * 9 + k] != NPTS) << k;
            atomicAdd(&lh[pat], 1);
        }
        __syncthreads();
        hist_t[t * HSTRIDE + b] = lh[t];
        hist_t[(t + 256) * HSTRIDE + b] = lh[t + 256];
    }
}

// ---- sort B1: per-pattern exclusive scan over blocks (in-place) + zero sacc --
__global__ void k_scan1(int* __restrict__ hist_t, int* __restrict__ tot,
                        unsigned long long* __restrict__ sacc) {
    const int p = blockIdx.x;
    const int lane = threadIdx.x;
    if (lane == 0) {                      // zero stats accumulators (1280 = 512+512+256)
        sacc[p] = 0ULL; sacc[512 + p] = 0ULL;
        if (p < 256) sacc[1024 + p] = 0ULL;
    }
    int run = 0;
    for (int c = 0; c < 10; c++) {
        const int i = c * 64 + lane;
        const int orig = (i < NBLK) ? hist_t[p * HSTRIDE + i] : 0;
        int v = orig;
        for (int d = 1; d < 64; d <<= 1) {
            const int w = __shfl_up(v, d);
            if (lane >= d) v += w;
        }
        if (i < NBLK) hist_t[p * HSTRIDE + i] = run + v - orig;
        run += __shfl(v, 63);
    }
    if (lane == 0) tot[p] = run;
}

// ---- sort C: base-scan (fused) + stable rank-scatter into perm ---------------
__global__ __launch_bounds__(512) void k_scatter(
    const int* __restrict__ nbr, const int* __restrict__ hist_t,
    const int* __restrict__ tot, int* __restrict__ perm) {
    __shared__ int pat_s[256];
    __shared__ int bs[512];
    const int t = threadIdx.x, b = blockIdx.x;
    const int v0 = tot[t];
    bs[t] = v0;
    __syncthreads();
    for (int d = 1; d < 512; d <<= 1) {
        const int w = (t >= d) ? bs[t - d] : 0;
        __syncthreads();
        bs[t] += w;
        __syncthreads();
    }
    const int base_t = bs[t] - v0;        // exclusive prefix
    __syncthreads();
    bs[t] = base_t;
    const int n = b * 256 + (t & 255);
    int pat = -1;
    if (t < 256) {
        if (n < NPTS) {
            pat = 0;
#pragma unroll
            for (int k = 0; k < 9; k++) pat |= (nbr[n * 9 + k] != NPTS) << k;
        }
        pat_s[t] = pat;
    }
    __syncthreads();
    if (t < 256 && n < NPTS) {
        int rank = 0;
        for (int j = 0; j < 256; j++) rank += (j < t) & (pat_s[j] == pat);
        perm[bs[pat] + hist_t[pat * HSTRIDE + b] + rank] = n;
    }
}

// ------- pass 3: sparse gather-GEMM (R12 core), scatter full rows to [n][640] --
__global__ __launch_bounds__(512, 4) void k_gemm(
    const unsigned short* __restrict__ xbf,
    const unsigned short* __restrict__ w1t,
    const int* __restrict__ nbr,
    const int* __restrict__ perm,
    unsigned short* __restrict__ accw2,
    unsigned long long* __restrict__ sacc)
{
    // A dbuf shorts [0,8192) ; B dbuf shorts [8192,28672)
    // epilogue alias: C 128x168 shorts [0,21504)
    __shared__ unsigned short ABC[28672];            // 57,344 B
    __shared__ int nbr_s[9 * 128];
    __shared__ int perm_s[128];
    __shared__ int mask_s;

    const int tid = threadIdx.x;
    const int wid = tid >> 6;
    const int lane = tid & 63;
    const int bm = blockIdx.x;
    const int b2 = blockIdx.y;              // which 320-col half
    const int tile = (bm * 331) % NTILES;   // spread heavy tiles (331 coprime to 1172)
    const int tile0 = tile * 128;

    if (tid == 0) mask_s = 0;
    if (tid < 128) {
        const int gr = tile0 + tid;
        perm_s[tid] = (gr < NPTS) ? perm[gr] : NPTS;
    }
    __syncthreads();
    if (tid < 128) {
        const int prow = perm_s[tid];
        int pat = 0;
#pragma unroll
        for (int k = 0; k < 9; k++) {
            const int v = (prow < NPTS) ? nbr[prow * 9 + k] : NPTS;
            nbr_s[k * 128 + tid] = v;
            pat |= (v != NPTS) << k;
        }
        if (pat) atomicOr(&mask_s, pat);
    }
    __syncthreads();
    const int mask = mask_s | 16;
    const int steps = 4 * __builtin_popcount(mask);

    const int RM = (wid >> 2) * 64;          // 2 row-groups of 64
    const int CNl = (wid & 3) * 80;          // 4 col-groups of 80
    const int lr16 = lane >> 2;              // staging: 16 rows/segment
    const int lb = lane & 3;                 // staging: 4 x 16B blocks/row
    const int jswS = (lb ^ ((lr16 >> 1) & 3)) * 8;   // A source swizzle

    f32x4 acc[4][5];
#pragma unroll
    for (int m = 0; m < 4; m++)
#pragma unroll
        for (int n = 0; n < 5; n++) acc[m][n] = f32x4{0.f, 0.f, 0.f, 0.f};

    // stage one BK=32 K-slab: A 8 segs + B 20 segs of 1 KB
    auto stage = [&](int buf, int kn, int q) {
#pragma unroll
        for (int j = 0; j < 4; ++j) {
            const int g = wid + 8 * j;               // wave-uniform
            if (g < 8) {                             // A rows g*16..+15
                const int r = g * 16 + lr16;
                const int idx = nbr_s[kn * 128 + r];
                gload16(xbf + (size_t)idx * 128 + q * 32 + jswS,
                        (void*)(ABC + buf * 4096 + g * 512));
            } else if (g < 28) {                     // B cols (g-8)*16..+15
                const int gb = g - 8;
                const int lc = gb * 16 + lr16;
                gload16(w1t + (size_t)(b2 * 320 + lc) * KTOT + (kn * 4 + q) * 32 + lb * 8,
                        (void*)(ABC + 8192 + buf * 10240 + gb * 512));
            }
        }
    };

    const int rlo = lane & 15;
    const int jsw = (((lane >> 4) ^ ((rlo >> 1) & 3))) * 8;  // read swizzle

    auto compute = [&](int buf) {
        const unsigned short* Ab = ABC + buf * 4096;
        const unsigned short* Bb = ABC + 8192 + buf * 10240;
        bf16x8 a[4];
#pragma unroll
        for (int m = 0; m < 4; m++)
            a[m] = *reinterpret_cast<const bf16x8*>(&Ab[(RM + m * 16 + rlo) * 32 + jsw]);
#pragma unroll
        for (int n = 0; n < 5; n++) {
            const bf16x8 b = *reinterpret_cast<const bf16x8*>(&Bb[(CNl + n * 16 + rlo) * 32 + jsw]);
#pragma unroll
            for (int m = 0; m < 4; m++)
                acc[m][n] = __builtin_amdgcn_mfma_f32_16x16x32_bf16(a[m], b, acc[m][n], 0, 0, 0);
        }
    };

    // walk (kn, q=0..3) over set bits of mask; prefetch-before-compute
    int ckn = __builtin_ctz(mask), cq = 0, rem = mask & (mask - 1), buf = 0;
    stage(0, ckn, 0);
    __syncthreads();
    for (int i = 0; i < steps; i++) {
        int nkn, nq, nrem;
        if (cq < 3) { nkn = ckn; nq = cq + 1; nrem = rem; }
        else { nkn = rem ? __builtin_ctz(rem) : 0; nq = 0; nrem = rem & (rem - 1); }
        if (i + 1 < steps) stage(buf ^ 1, nkn, nq);
        compute(buf);
        __syncthreads();
        ckn = nkn; cq = nq; rem = nrem; buf ^= 1;
    }

    // ---- per-column sums/sumsq -> fixed-point int64 atomics (deterministic) ----
    float sn[5], qn[5];
#pragma unroll
    for (int n = 0; n < 5; n++) {
        float s = 0.f, q = 0.f;
#pragma unroll
        for (int m = 0; m < 4; m++)
#pragma unroll
            for (int r = 0; r < 4; r++) { const float v = acc[m][n][r]; s += v; q += v * v; }
        s += __shfl_xor(s, 16); s += __shfl_xor(s, 32);
        q += __shfl_xor(q, 16); q += __shfl_xor(q, 32);
        sn[n] = s; qn[n] = q;
    }
    if (lane < 16) {
#pragma unroll
        for (int n = 0; n < 5; n++) {
            const int gcol = b2 * 320 + CNl + n * 16 + lane;
            atomicAdd(&sacc[gcol],
                      (unsigned long long)__double2ll_rn((double)sn[n] * FXSCALE));
            atomicAdd(&sacc[640 + gcol],
                      (unsigned long long)__double2ll_rn((double)qn[n] * FXSCALE));
        }
    }

    // ---- C store via LDS transpose: scatter 640-B half-rows to original order --
    unsigned short* C = (unsigned short*)ABC;            // 128 x 168 per pass
#pragma unroll
    for (int p = 0; p < 2; ++p) {
        __syncthreads();
        if (((wid >> 1) & 1) == p) {                     // waves owning cols p*160..+159
            const int colbase = CNl - p * 160;           // 0 or 80
#pragma unroll
            for (int m = 0; m < 4; m++) {
                const int row = RM + m * 16 + (lane >> 4) * 4;
#pragma unroll
                for (int n = 0; n < 5; n++) {
                    const int col = colbase + n * 16 + rlo;
#pragma unroll
                    for (int r = 0; r < 4; r++)
                        C[(row + r) * 168 + col] = f2bf(acc[m][n][r]);
                }
            }
        }
        __syncthreads();
#pragma unroll
        for (int j = 0; j < 5; j++) {
            const int chunk = tid + 512 * j;             // 2560 = 128 rows x 20 chunks
            const int row = chunk / 20, cc = chunk % 20;
            const int prow = perm_s[row];                // ORIGINAL row (random, full-line runs)
            if (prow < NPTS) {
                const int col = b2 * 320 + p * 160 + cc * 8;
                __builtin_nontemporal_store(*(const u16x8*)&C[row * 168 + cc * 8],
                    (u16x8*)(accw2 + (size_t)prow * 640 + col));
            }
        }
    }
}

// ------- pass 4: stats + normalize + relu + W2 + bias + mask (all heads) ------
// Fully sequential: rows n in original order, cached loads (L1 absorbs stride).
__global__ __launch_bounds__(512) void k_out(
    const unsigned short* __restrict__ accw2,
    const unsigned long long* __restrict__ sacc,
    const float* __restrict__ gamma, const float* __restrict__ beta,
    const float* __restrict__ W2, const float* __restrict__ b2,
    float* __restrict__ out)
{
    __shared__ float sc[640], sh[640], w2s[1920], b2s[15];
    __shared__ float red[128][4][6];
    const int t = threadIdx.x;
    for (int c = t; c < 640; c += 512) {
        const double s = (double)(long long)sacc[c] * (1.0 / FXSCALE);
        const double q = (double)(long long)sacc[640 + c] * (1.0 / FXSCALE);
        const double mean = s * (1.0 / NPTS);
        const double var = q * (1.0 / NPTS) - mean * mean;
        const float rstd = (float)(1.0 / sqrt(var + (double)EPSV));
        const float g = gamma[c];
        sc[c] = rstd * g;
        sh[c] = beta[c] - (float)mean * rstd * g;
        w2s[c * 3 + 0] = W2[c * 3 + 0];
        w2s[c * 3 + 1] = W2[c * 3 + 1];
        w2s[c * 3 + 2] = W2[c * 3 + 2];
    }
    if (t < 15) b2s[t] = b2[t];
    __syncthreads();

    const int row = t >> 2;                   // 128 rows/block, 4 threads/row
    const int seg = t & 3;                    // 160 cols each; head splits at ccb
    const int n0 = blockIdx.x * 128 + row;    // sequential original row
    const int ccb = 16 - seg * 4;             // 16B-chunk index where head increments
    float o0[3] = {0.f, 0.f, 0.f}, o1[3] = {0.f, 0.f, 0.f};
    if (n0 < NPTS) {
        const unsigned short* rp = accw2 + (size_t)n0 * 640 + seg * 160;
        for (int cc = 0; cc < ccb; cc++) {    // section 0 -> head seg
            const u16x8 v = *(const u16x8*)(rp + cc * 8);       // cached load
#pragma unroll
            for (int j = 0; j < 8; j++) {
                const int c = seg * 160 + cc * 8 + j;
                const float a = __uint_as_float(((unsigned int)v[j]) << 16);
                const float hc = fmaxf(fmaf(a, sc[c], sh[c]), 0.f);
                o0[0] = fmaf(hc, w2s[c * 3 + 0], o0[0]);
                o0[1] = fmaf(hc, w2s[c * 3 + 1], o0[1]);
                o0[2] = fmaf(hc, w2s[c * 3 + 2], o0[2]);
            }
        }
        for (int cc = ccb; cc < 20; cc++) {   // section 1 -> head seg+1
            const u16x8 v = *(const u16x8*)(rp + cc * 8);       // cached load
#pragma unroll
            for (int j = 0; j < 8; j++) {
                const int c = seg * 160 + cc * 8 + j;
                const float a = __uint_as_float(((unsigned int)v[j]) << 16);
                const float hc = fmaxf(fmaf(a, sc[c], sh[c]), 0.f);
                o1[0] = fmaf(hc, w2s[c * 3 + 0], o1[0]);
                o1[1] = fmaf(hc, w2s[c * 3 + 1], o1[1]);
                o1[2] = fmaf(hc, w2s[c * 3 + 2], o1[2]);
            }
        }
    }
    red[row][seg][0] = o0[0]; red[row][seg][1] = o0[1]; red[row][seg][2] = o0[2];
    red[row][seg][3] = o1[0]; red[row][seg][4] = o1[1]; red[row][seg][5] = o1[2];
    __syncthreads();

    // combine: head h <- seg h-1 section1 + seg h section0 ; write coalesced per head
    for (int idx = t; idx < 640; idx += 512) {
        const int h = idx >> 7, rw = idx & 127;
        const int n = blockIdx.x * 128 + rw;
        if (n < NPTS) {
            float a0 = b2s[h * 3 + 0], a1 = b2s[h * 3 + 1], a2 = b2s[h * 3 + 2];
            if (h >= 1) { a0 += red[rw][h - 1][3]; a1 += red[rw][h - 1][4]; a2 += red[rw][h - 1][5]; }
            if (h <= 3) { a0 += red[rw][h][0]; a1 += red[rw][h][1]; a2 += red[rw][h][2]; }
            const int noc = (h == 2) ? 1 : ((h == 1 || h == 4) ? 2 : 3);
            const size_t ob = ((size_t)h * NPTS + n) * 3;
            out[ob + 0] = (noc > 0) ? a0 : 0.f;
            out[ob + 1] = (noc > 1) ? a1 : 0.f;
            out[ob + 2] = (noc > 2) ? a2 : 0.f;
        }
    }
}

__global__ void k_sentinel(float* __restrict__ out, int n) {
    const int i = blockIdx.x * 256 + threadIdx.x;
    if (i < n) out[i] = 12345.0f;
}

extern "C" void kernel_launch(void* const* d_in, const int* in_sizes, int n_in,
                              void* d_out, int out_size, void* d_ws, size_t ws_size,
                              hipStream_t stream) {
    const float* x     = (const float*)d_in[0];
    const int*   nbr   = (const int*)d_in[1];
    const float* W1    = (const float*)d_in[2];
    const float* gamma = (const float*)d_in[3];
    const float* beta  = (const float*)d_in[4];
    const float* W2    = (const float*)d_in[5];
    const float* b2    = (const float*)d_in[6];
    float* out = (float*)d_out;

    if (ws_size < WS_NEEDED) {
        k_sentinel<<<(out_size + 255) / 256, 256, 0, stream>>>(out, out_size);
        return;
    }

    char* ws = (char*)d_ws;
    unsigned short* xbf      = (unsigned short*)(ws);
    unsigned short* w1t      = (unsigned short*)(ws + 38404096);
    unsigned short* accw2    = (unsigned short*)(ws + 39878656);
    int*            hist_t   = (int*)(ws + 39878656);            // aliases accw2 (pre-GEMM)
    int*            tot      = (int*)(ws + 39878656 + 2097152);  // aliases accw2 (pre-GEMM)
    unsigned long long* sacc = (unsigned long long*)(ws + 231899136);
    int*            perm     = (int*)(ws + 231909376);

    k_pre<<<12842, 256, 0, stream>>>(x, xbf, W1, w1t, nbr, hist_t);
    k_scan1<<<512, 64, 0, stream>>>(hist_t, tot, sacc);
    k_scatter<<<NBLK, 512, 0, stream>>>(nbr, hist_t, tot, perm);
    k_gemm<<<dim3(NTILES, 2), 512, 0, stream>>>(xbf, w1t, nbr, perm, accw2, sacc);
    k_out<<<NTILES, 512, 0, stream>>>(accw2, sacc, gamma, beta, W2, b2, out);
}

// Round 16
// 304.695 us; speedup vs baseline: 1.3795x; 1.1697x over previous
//
#include <hip/hip_runtime.h>

#define NPTS 150000
#define NHEAD 5
#define KTOT 1152
#define NTILES 1172   // ceil(150000/128)
#define NBLK 586      // ceil(150000/256)
#define HSTRIDE 592   // padded NBLK for hist_t rows
#define EPSV 1e-5f
#define FXSCALE 1048576.0   // 2^20 fixed-point for deterministic atomics

typedef __bf16 bf16x8 __attribute__((ext_vector_type(8)));
typedef float f32x4 __attribute__((ext_vector_type(4)));
typedef unsigned short u16x8 __attribute__((ext_vector_type(8)));

// ws layout (bytes):
//   xbf      @ 0          : 150016*128*2      = 38,404,096
//   w1t      @ 38404096   : 5*128*1152*2      =  1,474,560   (pre-swizzled B^T)
//   accw2    @ 39878656   : 150016*640*2      = 192,020,480  (TILE order, [gr][640])
//     pre-GEMM aliases: hist_t @ accw2+0 (512*592*4) ; tot @ +2,097,152 (2 KB)
//   sacc     @ 231899136  : 1280*8            =     10,240   (int64 fixed-point stats)
//   perm     @ 231909376  : 150000*4          =    600,000
#define WS_NEEDED 232509376UL

__device__ __forceinline__ unsigned short f2bf(float f) {
    unsigned int u = __float_as_uint(f);
    u += 0x7FFFu + ((u >> 16) & 1u);          // round-to-nearest-even
    return (unsigned short)(u >> 16);
}

__device__ __forceinline__ void gload16(const void* g, void* l) {
    __builtin_amdgcn_global_load_lds((const __attribute__((address_space(1))) void*)g,
                                     (__attribute__((address_space(3))) void*)l, 16, 0, 0);
}

// ---- fused pre-pass: convert x -> xbf | W1 -> w1t (swizzled) | pattern hist --
__global__ void k_pre(const float* __restrict__ x, unsigned short* __restrict__ xbf,
                      const float* __restrict__ W1, unsigned short* __restrict__ w1t,
                      const int* __restrict__ nbr, int* __restrict__ hist_t) {
    __shared__ int lh[512];
    const int bid = blockIdx.x;
    const int t = threadIdx.x;
    if (bid < 9376) {                     // ---- convert ----
        const size_t i8 = (size_t)bid * 256 + t;
        const size_t base = i8 * 8;
        if (base >= (size_t)(NPTS + 1) * 128) return;
        if (base < (size_t)NPTS * 128) {
            const f32x4 v0 = __builtin_nontemporal_load((const f32x4*)(x + base));
            const f32x4 v1 = __builtin_nontemporal_load((const f32x4*)(x + base + 4));
            u16x8 o;
            o[0] = f2bf(v0[0]); o[1] = f2bf(v0[1]); o[2] = f2bf(v0[2]); o[3] = f2bf(v0[3]);
            o[4] = f2bf(v1[0]); o[5] = f2bf(v1[1]); o[6] = f2bf(v1[2]); o[7] = f2bf(v1[3]);
            *(u16x8*)(xbf + base) = o;
        } else {
            u16x8 z = {0,0,0,0,0,0,0,0};
            *(u16x8*)(xbf + base) = z;
        }
    } else if (bid < 9376 + 2880) {       // ---- w1t (B^T, 4-block swizzle/32-short seg) ----
        const int idx = (bid - 9376) * 256 + t;
        const int d = idx & 127;
        const int c = (idx >> 7) & 127;
        const int hk = idx >> 14;
        const int k = hk % 9, h = hk / 9;
        const int col = h * 128 + d;
        const int p = k * 128 + c;
        const int s32 = p >> 5;
        const int j0 = (p >> 3) & 3;
        const int jj = j0 ^ ((col >> 1) & 3);
        w1t[(size_t)col * KTOT + s32 * 32 + jj * 8 + (p & 7)] = f2bf(W1[idx]);
    } else {                              // ---- hist ----
        const int b = bid - 12256;
        lh[t] = 0; lh[t + 256] = 0;
        __syncthreads();
        const int n = b * 256 + t;
        if (n < NPTS) {
            int pat = 0;
#pragma unroll
            for (int k = 0; k < 9; k++) pat |= (nbr[n * 9 + k] != NPTS) << k;
            atomicAdd(&lh[pat], 1);
        }
        __syncthreads();
        hist_t[t * HSTRIDE + b] = lh[t];
        hist_t[(t + 256) * HSTRIDE + b] = lh[t + 256];
    }
}

// ---- sort B1: per-pattern exclusive scan over blocks (in-place) + zero sacc --
__global__ void k_scan1(int* __restrict__ hist_t, int* __restrict__ tot,
                        unsigned long long* __restrict__ sacc) {
    const int p = blockIdx.x;
    const int lane = threadIdx.x;
    if (lane == 0) {                      // zero stats accumulators (1280 = 512+512+256)
        sacc[p] = 0ULL; sacc[512 + p] = 0ULL;
        if (p < 256) sacc[1024 + p] = 0ULL;
    }
    int run = 0;
    for (int c = 0; c < 10; c++) {
        const int i = c * 64 + lane;
        const int orig = (i < NBLK) ? hist_t[p * HSTRIDE + i] : 0;
        int v = orig;
        for (int d = 1; d < 64; d <<= 1) {
            const int w = __shfl_up(v, d);
            if (lane >= d) v += w;
        }
        if (i < NBLK) hist_t[p * HSTRIDE + i] = run + v - orig;
        run += __shfl(v, 63);
    }
    if (lane == 0) tot[p] = run;
}

// ---- sort C: base-scan (fused) + stable rank-scatter into perm ---------------
__global__ __launch_bounds__(512) void k_scatter(
    const int* __restrict__ nbr, const int* __restrict__ hist_t,
    const int* __restrict__ tot, int* __restrict__ perm) {
    __shared__ int pat_s[256];
    __shared__ int bs[512];
    const int t = threadIdx.x, b = blockIdx.x;
    const int v0 = tot[t];
    bs[t] = v0;
    __syncthreads();
    for (int d = 1; d < 512; d <<= 1) {
        const int w = (t >= d) ? bs[t - d] : 0;
        __syncthreads();
        bs[t] += w;
        __syncthreads();
    }
    const int base_t = bs[t] - v0;        // exclusive prefix
    __syncthreads();
    bs[t] = base_t;
    const int n = b * 256 + (t & 255);
    int pat = -1;
    if (t < 256) {
        if (n < NPTS) {
            pat = 0;
#pragma unroll
            for (int k = 0; k < 9; k++) pat |= (nbr[n * 9 + k] != NPTS) << k;
        }
        pat_s[t] = pat;
    }
    __syncthreads();
    if (t < 256 && n < NPTS) {
        int rank = 0;
        for (int j = 0; j < 256; j++) rank += (j < t) & (pat_s[j] == pat);
        perm[bs[pat] + hist_t[pat * HSTRIDE + b] + rank] = n;
    }
}

// ------- pass 3: sparse gather-GEMM (R12 core), dense tile-order C-store ------
__global__ __launch_bounds__(512, 4) void k_gemm(
    const unsigned short* __restrict__ xbf,
    const unsigned short* __restrict__ w1t,
    const int* __restrict__ nbr,
    const int* __restrict__ perm,
    unsigned short* __restrict__ accw2,
    unsigned long long* __restrict__ sacc)
{
    // A dbuf shorts [0,8192) ; B dbuf shorts [8192,28672)
    // epilogue alias: C 128x168 shorts [0,21504)
    __shared__ unsigned short ABC[28672];            // 57,344 B
    __shared__ int nbr_s[9 * 128];
    __shared__ int perm_s[128];
    __shared__ int mask_s;

    const int tid = threadIdx.x;
    const int wid = tid >> 6;
    const int lane = tid & 63;
    const int bm = blockIdx.x;
    const int b2 = blockIdx.y;              // which 320-col half
    const int tile = (bm * 331) % NTILES;   // spread heavy tiles (331 coprime to 1172)
    const int tile0 = tile * 128;

    if (tid == 0) mask_s = 0;
    if (tid < 128) {
        const int gr = tile0 + tid;
        perm_s[tid] = (gr < NPTS) ? perm[gr] : NPTS;
    }
    __syncthreads();
    if (tid < 128) {
        const int prow = perm_s[tid];
        int pat = 0;
#pragma unroll
        for (int k = 0; k < 9; k++) {
            const int v = (prow < NPTS) ? nbr[prow * 9 + k] : NPTS;
            nbr_s[k * 128 + tid] = v;
            pat |= (v != NPTS) << k;
        }
        if (pat) atomicOr(&mask_s, pat);
    }
    __syncthreads();
    const int mask = mask_s | 16;
    const int steps = 4 * __builtin_popcount(mask);

    const int RM = (wid >> 2) * 64;          // 2 row-groups of 64
    const int CNl = (wid & 3) * 80;          // 4 col-groups of 80
    const int lr16 = lane >> 2;              // staging: 16 rows/segment
    const int lb = lane & 3;                 // staging: 4 x 16B blocks/row
    const int jswS = (lb ^ ((lr16 >> 1) & 3)) * 8;   // A source swizzle

    f32x4 acc[4][5];
#pragma unroll
    for (int m = 0; m < 4; m++)
#pragma unroll
        for (int n = 0; n < 5; n++) acc[m][n] = f32x4{0.f, 0.f, 0.f, 0.f};

    // stage one BK=32 K-slab: A 8 segs + B 20 segs of 1 KB
    auto stage = [&](int buf, int kn, int q) {
#pragma unroll
        for (int j = 0; j < 4; ++j) {
            const int g = wid + 8 * j;               // wave-uniform
            if (g < 8) {                             // A rows g*16..+15
                const int r = g * 16 + lr16;
                const int idx = nbr_s[kn * 128 + r];
                gload16(xbf + (size_t)idx * 128 + q * 32 + jswS,
                        (void*)(ABC + buf * 4096 + g * 512));
            } else if (g < 28) {                     // B cols (g-8)*16..+15
                const int gb = g - 8;
                const int lc = gb * 16 + lr16;
                gload16(w1t + (size_t)(b2 * 320 + lc) * KTOT + (kn * 4 + q) * 32 + lb * 8,
                        (void*)(ABC + 8192 + buf * 10240 + gb * 512));
            }
        }
    };

    const int rlo = lane & 15;
    const int jsw = (((lane >> 4) ^ ((rlo >> 1) & 3))) * 8;  // read swizzle

    auto compute = [&](int buf) {
        const unsigned short* Ab = ABC + buf * 4096;
        const unsigned short* Bb = ABC + 8192 + buf * 10240;
        bf16x8 a[4];
#pragma unroll
        for (int m = 0; m < 4; m++)
            a[m] = *reinterpret_cast<const bf16x8*>(&Ab[(RM + m * 16 + rlo) * 32 + jsw]);
#pragma unroll
        for (int n = 0; n < 5; n++) {
            const bf16x8 b = *reinterpret_cast<const bf16x8*>(&Bb[(CNl + n * 16 + rlo) * 32 + jsw]);
#pragma unroll
            for (int m = 0; m < 4; m++)
                acc[m][n] = __builtin_amdgcn_mfma_f32_16x16x32_bf16(a[m], b, acc[m][n], 0, 0, 0);
        }
    };

    // walk (kn, q=0..3) over set bits of mask; prefetch-before-compute
    int ckn = __builtin_ctz(mask), cq = 0, rem = mask & (mask - 1), buf = 0;
    stage(0, ckn, 0);
    __syncthreads();
    for (int i = 0; i < steps; i++) {
        int nkn, nq, nrem;
        if (cq < 3) { nkn = ckn; nq = cq + 1; nrem = rem; }
        else { nkn = rem ? __builtin_ctz(rem) : 0; nq = 0; nrem = rem & (rem - 1); }
        if (i + 1 < steps) stage(buf ^ 1, nkn, nq);
        compute(buf);
        __syncthreads();
        ckn = nkn; cq = nq; rem = nrem; buf ^= 1;
    }

    // ---- per-column sums/sumsq -> fixed-point int64 atomics (deterministic) ----
    float sn[5], qn[5];
#pragma unroll
    for (int n = 0; n < 5; n++) {
        float s = 0.f, q = 0.f;
#pragma unroll
        for (int m = 0; m < 4; m++)
#pragma unroll
            for (int r = 0; r < 4; r++) { const float v = acc[m][n][r]; s += v; q += v * v; }
        s += __shfl_xor(s, 16); s += __shfl_xor(s, 32);
        q += __shfl_xor(q, 16); q += __shfl_xor(q, 32);
        sn[n] = s; qn[n] = q;
    }
    if (lane < 16) {
#pragma unroll
        for (int n = 0; n < 5; n++) {
            const int gcol = b2 * 320 + CNl + n * 16 + lane;
            atomicAdd(&sacc[gcol],
                      (unsigned long long)__double2ll_rn((double)sn[n] * FXSCALE));
            atomicAdd(&sacc[640 + gcol],
                      (unsigned long long)__double2ll_rn((double)qn[n] * FXSCALE));
        }
    }

    // ---- C store via LDS transpose into dense tile-order [gr][640] rows -------
    unsigned short* C = (unsigned short*)ABC;            // 128 x 168 per pass
#pragma unroll
    for (int p = 0; p < 2; ++p) {
        __syncthreads();
        if (((wid >> 1) & 1) == p) {                     // waves owning cols p*160..+159
            const int colbase = CNl - p * 160;           // 0 or 80
#pragma unroll
            for (int m = 0; m < 4; m++) {
                const int row = RM + m * 16 + (lane >> 4) * 4;
#pragma unroll
                for (int n = 0; n < 5; n++) {
                    const int col = colbase + n * 16 + rlo;
#pragma unroll
                    for (int r = 0; r < 4; r++)
                        C[(row + r) * 168 + col] = f2bf(acc[m][n][r]);
                }
            }
        }
        __syncthreads();
#pragma unroll
        for (int j = 0; j < 5; j++) {
            const int chunk = tid + 512 * j;             // 2560 = 128 rows x 20 chunks
            const int row = chunk / 20, cc = chunk % 20;
            const int gr = tile0 + row;                  // dense tile-order row (<150016)
            const int col = b2 * 320 + p * 160 + cc * 8;
            __builtin_nontemporal_store(*(const u16x8*)&C[row * 168 + cc * 8],
                (u16x8*)(accw2 + (size_t)gr * 640 + col));
        }
    }
}

// ------- pass 4: stats + normalize + relu + W2 + bias + mask (all heads) ------
// Sequential tile-order reads (dense); scatter-writes 9 MB output via perm.
__global__ __launch_bounds__(512) void k_out(
    const unsigned short* __restrict__ accw2,
    const int* __restrict__ perm,
    const unsigned long long* __restrict__ sacc,
    const float* __restrict__ gamma, const float* __restrict__ beta,
    const float* __restrict__ W2, const float* __restrict__ b2,
    float* __restrict__ out)
{
    // padded layouts: seg s starts at s*168 (sc/sh) and s*488 (w2s) -> %32==8 bank skew
    __shared__ float scp[672], shp[672], w2sp[1952], b2s[15];
    __shared__ float red[4][128][6];
    __shared__ int op_s[128];
    const int t = threadIdx.x;
    for (int c = t; c < 640; c += 512) {
        const double s = (double)(long long)sacc[c] * (1.0 / FXSCALE);
        const double q = (double)(long long)sacc[640 + c] * (1.0 / FXSCALE);
        const double mean = s * (1.0 / NPTS);
        const double var = q * (1.0 / NPTS) - mean * mean;
        const float rstd = (float)(1.0 / sqrt(var + (double)EPSV));
        const float g = gamma[c];
        const int sg = c / 160, off = c % 160;
        scp[sg * 168 + off] = rstd * g;
        shp[sg * 168 + off] = beta[c] - (float)mean * rstd * g;
        w2sp[sg * 488 + off * 3 + 0] = W2[c * 3 + 0];
        w2sp[sg * 488 + off * 3 + 1] = W2[c * 3 + 1];
        w2sp[sg * 488 + off * 3 + 2] = W2[c * 3 + 2];
    }
    if (t < 15) b2s[t] = b2[t];
    if (t < 128) {
        const int gr = blockIdx.x * 128 + t;
        op_s[t] = (gr < NPTS) ? perm[gr] : -1;
    }
    __syncthreads();

    const int row = t >> 2;                   // 128 rows/block, 4 threads/row
    const int seg = t & 3;                    // 160 cols each; head splits at ccb
    const int gr = blockIdx.x * 128 + row;    // dense tile-order row
    const int ccb = 16 - seg * 4;             // 16B-chunk where head increments
    float o0[3] = {0.f, 0.f, 0.f}, o1[3] = {0.f, 0.f, 0.f};
    if (op_s[row] >= 0) {
        const unsigned short* rp = accw2 + (size_t)gr * 640 + seg * 160;
        const float* scb = scp + seg * 168;
        const float* shb = shp + seg * 168;
        const float* w2b = w2sp + seg * 488;
#pragma unroll
        for (int cc = 0; cc < 20; cc++) {
            const u16x8 v = *(const u16x8*)(rp + cc * 8);
            float t0 = 0.f, t1 = 0.f, t2 = 0.f;
#pragma unroll
            for (int j = 0; j < 8; j++) {
                const int off = cc * 8 + j;
                const float a = __uint_as_float(((unsigned int)v[j]) << 16);
                const float hc = fmaxf(fmaf(a, scb[off], shb[off]), 0.f);
                t0 = fmaf(hc, w2b[off * 3 + 0], t0);
                t1 = fmaf(hc, w2b[off * 3 + 1], t1);
                t2 = fmaf(hc, w2b[off * 3 + 2], t2);
            }
            if (cc < ccb) { o0[0] += t0; o0[1] += t1; o0[2] += t2; }
            else          { o1[0] += t0; o1[1] += t1; o1[2] += t2; }
        }
    }
    red[seg][row][0] = o0[0]; red[seg][row][1] = o0[1]; red[seg][row][2] = o0[2];
    red[seg][row][3] = o1[0]; red[seg][row][4] = o1[1]; red[seg][row][5] = o1[2];
    __syncthreads();

    // combine: head h <- seg h-1 section1 + seg h section0 ; scatter-write via perm
    for (int idx = t; idx < 640; idx += 512) {
        const int h = idx >> 7, rw = idx & 127;
        const int n = op_s[rw];
        if (n >= 0) {
            float a0 = b2s[h * 3 + 0], a1 = b2s[h * 3 + 1], a2 = b2s[h * 3 + 2];
            if (h >= 1) { a0 += red[h - 1][rw][3]; a1 += red[h - 1][rw][4]; a2 += red[h - 1][rw][5]; }
            if (h <= 3) { a0 += red[h][rw][0]; a1 += red[h][rw][1]; a2 += red[h][rw][2]; }
            const int noc = (h == 2) ? 1 : ((h == 1 || h == 4) ? 2 : 3);
            const size_t ob = ((size_t)h * NPTS + n) * 3;
            out[ob + 0] = (noc > 0) ? a0 : 0.f;
            out[ob + 1] = (noc > 1) ? a1 : 0.f;
            out[ob + 2] = (noc > 2) ? a2 : 0.f;
        }
    }
}

__global__ void k_sentinel(float* __restrict__ out, int n) {
    const int i = blockIdx.x * 256 + threadIdx.x;
    if (i < n) out[i] = 12345.0f;
}

extern "C" void kernel_launch(void* const* d_in, const int* in_sizes, int n_in,
                              void* d_out, int out_size, void* d_ws, size_t ws_size,
                              hipStream_t stream) {
    const float* x     = (const float*)d_in[0];
    const int*   nbr   = (const int*)d_in[1];
    const float* W1    = (const float*)d_in[2];
    const float* gamma = (const float*)d_in[3];
    const float* beta  = (const float*)d_in[4];
    const float* W2    = (const float*)d_in[5];
    const float* b2    = (const float*)d_in[6];
    float* out = (float*)d_out;

    if (ws_size < WS_NEEDED) {
        k_sentinel<<<(out_size + 255) / 256, 256, 0, stream>>>(out, out_size);
        return;
    }

    char* ws = (char*)d_ws;
    unsigned short* xbf      = (unsigned short*)(ws);
    unsigned short* w1t      = (unsigned short*)(ws + 38404096);
    unsigned short* accw2    = (unsigned short*)(ws + 39878656);
    int*            hist_t   = (int*)(ws + 39878656);            // aliases accw2 (pre-GEMM)
    int*            tot      = (int*)(ws + 39878656 + 2097152);  // aliases accw2 (pre-GEMM)
    unsigned long long* sacc = (unsigned long long*)(ws + 231899136);
    int*            perm     = (int*)(ws + 231909376);

    k_pre<<<12842, 256, 0, stream>>>(x, xbf, W1, w1t, nbr, hist_t);
    k_scan1<<<512, 64, 0, stream>>>(hist_t, tot, sacc);
    k_scatter<<<NBLK, 512, 0, stream>>>(nbr, hist_t, tot, perm);
    k_gemm<<<dim3(NTILES, 2), 512, 0, stream>>>(xbf, w1t, nbr, perm, accw2, sacc);
    k_out<<<NTILES, 512, 0, stream>>>(accw2, perm, sacc, gamma, beta, W2, b2, out);
}